// Round 8
// baseline (82.511 us; speedup 1.0000x reference)
//
#include <hip/hip_runtime.h>

// SDT forward, fp16 MFMA (fp32 accumulate), v9: v8 + XCD-local wt/vt
// replication. sdt_pre writes 8 copies (one per XCD, block b -> copy b&7,
// bid round-robins XCDs on MI355X); sdt_main block b reads copy b&7 ->
// wt/vt reads are same-XCD L2 hits instead of cross-XCD L3 (~4-6us term).
// 8 x 288 KB = 2.3 MB in workspace. Numerics bit-identical to v4..v8.
// Lessons: coop grid.sync +40us (v3); fp32 scalar gather +35us (v5);
// extra waves/SIMD 0 (v6); in-loop VMEM ~0 (v7); pre-parallel+vt-hide -1 (v8).
// Layouts (HW-verified): A/B^T lane&15->row(n), (lane>>4)*8->k;
// C/D: col=lane&15, row=(lane>>4)*4+reg.

typedef __attribute__((ext_vector_type(8))) _Float16 half8;
typedef __attribute__((ext_vector_type(4))) _Float16 half4;
typedef __attribute__((ext_vector_type(2))) _Float16 half2v;
typedef __attribute__((ext_vector_type(4))) float floatx4;

constexpr int O = 64;
constexpr int XSTR = 520;   // x-tile LDS row stride (halfs): 1040 B
constexpr int PSTR = 280;   // P_h row stride (halfs): 560 B (16B-aligned)
constexpr int LSTR = 260;   // L_s row stride (floats)
constexpr int CPY = 147456; // halfs per copy: wt 131072 (256 KB) + vt 16384 (32 KB)

// ---- pre: 8 XCD-local copies of frag-major fp16 W^T / value^T ----
// wt layout: block (T*16+c) of 1024 B; lane=(q*16+r16); elem j:
//   wt[(T*16+c)*512 + lane*8 + j] = W[k= c*32+q*8+j][n= T*16+r16]
// 1088 blocks: copy = b&7 (XCD-local write), inner = b>>3 (0..135).
__global__ __launch_bounds__(512) void sdt_pre(
    const float* __restrict__ Ws, const float* __restrict__ value,
    _Float16* __restrict__ wt_all, float* __restrict__ reg_slot)
{
  const int b = blockIdx.x, t = threadIdx.x;
  const int copy = b & 7, inner = b >> 3;
  _Float16* wt = wt_all + (size_t)copy * CPY;
  _Float16* vt = wt + 131072;

  if (inner < 128) {                   // W: 4 k-rows per inner, coalesced reads
    const int k0 = inner * 4;
    const int n = t & 255, hf = t >> 8;            // hf: which kk-pair
    const int T = n >> 4, r = n & 15;
    const int kA = k0 + hf * 2;                    // first k of this pair
    const int c = kA >> 5, q = (kA >> 3) & 3, j0 = kA & 7;
    _Float16 v2h[2];
#pragma unroll
    for (int i = 0; i < 2; ++i) {
      float f = (n < 255) ? Ws[(size_t)(kA + i) * 255 + n] : 0.f;
      v2h[i] = (_Float16)f;
    }
    *(half2v*)&wt[(size_t)(T * 16 + c) * 512 + (q * 16 + r) * 8 + j0] =
        *(half2v*)v2h;
  } else {                             // value^T: 32 k-rows per inner
    const int k0 = (inner - 128) * 32;
#pragma unroll
    for (int j = 0; j < 4; ++j) {
      int e = t + j * 512;             // 0..2047
      int k = k0 + (e >> 6), n = e & 63;
      float f = value[(size_t)k * O + n];
      int T = n >> 4, r = n & 15, kc = k >> 5, q = (k >> 3) & 3, jj = k & 7;
      vt[(size_t)(T * 8 + kc) * 512 + (q * 16 + r) * 8 + jj] = (_Float16)f;
    }
    if (copy == 0 && inner == 128 && t == 0) *reg_slot = 0.f;
  }
}

__global__ __launch_bounds__(512, 1) void sdt_main(
    const float* __restrict__ x, const _Float16* __restrict__ wt_all,
    const float* __restrict__ bs,
    float* __restrict__ out, float* __restrict__ reg_out)
{
  // Disjoint LDS (no overlay): xh 33280 + L_s 33280 + P_h 17920 = 84480 B.
  __shared__ __align__(16) char smem[33280 + 33280 + 17920];
  _Float16* xh_s = (_Float16*)smem;               // [32][520]
  float*    L_s  = (float*)(smem + 33280);        // [32][260]
  _Float16* P_h  = (_Float16*)(smem + 66560);     // [32][280]
  __shared__ float red_s[8];

  const int t = threadIdx.x, lane = t & 63, w = t >> 6;   // 8 waves
  const int q = lane >> 4, r16 = lane & 15;
  const int R0 = blockIdx.x * 32;

  // XCD-local copy: same b&7 as the pre block that wrote it.
  const _Float16* wt = wt_all + (size_t)(blockIdx.x & 7) * CPY;
  const _Float16* vt = wt + 131072;

  // ---- issue x loads first (HBM, longest latency; oldest -> drain first) ----
  const int xrowi = t >> 4, xl4 = (t & 15) * 4;
  const float* xrow = x + (size_t)(R0 + xrowi) * 512;
  float4 xv[8];
#pragma unroll
  for (int i = 0; i < 8; ++i) xv[i] = *(const float4*)(xrow + xl4 + i * 64);

  // ---- preload ALL 16 B-chunks for both n-tiles (128 VGPRs) ----
  const _Float16* pb0 = wt + (size_t)(2 * w) * 16 * 512 + lane * 8;
  const _Float16* pb1 = wt + (size_t)(2 * w + 1) * 16 * 512 + lane * 8;
  half8 B0[16], B1[16];
#pragma unroll
  for (int c = 0; c < 16; ++c) {
    B0[c] = *(const half8*)(pb0 + c * 512);
    B1[c] = *(const half8*)(pb1 + c * 512);
  }

  // ---- convert + store x tile to LDS ----
#pragma unroll
  for (int i = 0; i < 8; ++i) {
    half4 h = {(_Float16)xv[i].x, (_Float16)xv[i].y,
               (_Float16)xv[i].z, (_Float16)xv[i].w};
    *(half4*)&xh_s[xrowi * XSTR + xl4 + i * 64] = h;
  }
  __syncthreads();   // barrier 1: x tile staged

  // ---- K-loop: 16 chunks of K=32, pure LDS + MFMA (no VMEM) ----
  floatx4 acc00 = {0,0,0,0}, acc01 = {0,0,0,0}, acc10 = {0,0,0,0}, acc11 = {0,0,0,0};
  const int a0off = r16 * XSTR + q * 8, a1off = (16 + r16) * XSTR + q * 8;

#pragma unroll
  for (int c = 0; c < 16; ++c) {
    half8 a0 = *(const half8*)&xh_s[a0off + c * 32];
    half8 a1 = *(const half8*)&xh_s[a1off + c * 32];
    acc00 = __builtin_amdgcn_mfma_f32_16x16x32_f16(a0, B0[c], acc00, 0, 0, 0);
    acc01 = __builtin_amdgcn_mfma_f32_16x16x32_f16(a0, B1[c], acc01, 0, 0, 0);
    acc10 = __builtin_amdgcn_mfma_f32_16x16x32_f16(a1, B0[c], acc10, 0, 0, 0);
    acc11 = __builtin_amdgcn_mfma_f32_16x16x32_f16(a1, B1[c], acc11, 0, 0, 0);
  }

  // ---- vt B-frag prefetch NOW: latency hides under the epilogue ----
  half8 VB[8];
  {
    const int tn = w >> 1;
    const _Float16* vb = vt + (size_t)(tn * 8) * 512 + lane * 8;
#pragma unroll
    for (int kc = 0; kc < 8; ++kc) VB[kc] = *(const half8*)(vb + kc * 512);
  }

  // ---- fused epilogue: bias + sigmoid + reg on registers ----
  const int c0 = w * 32 + r16, c1 = c0 + 16;   // c0 <= 239; c1 <= 255
  const bool v1ok = (c1 < 255);
  float pv00[4], pv01[4], pv10[4], pv11[4];
  float s0 = 0.f, s1 = 0.f;
  {
    const float b0 = bs[c0];
    const float b1 = v1ok ? bs[c1] : 0.f;
#pragma unroll
    for (int r = 0; r < 4; ++r) {
      float p;
      p = 1.f / (1.f + __expf(-(acc00[r] + b0))); pv00[r] = p;
      s0 += __logf(fmaxf(p * (1.f - p), 1e-5f));
      p = 1.f / (1.f + __expf(-(acc10[r] + b0))); pv10[r] = p;
      s0 += __logf(fmaxf(p * (1.f - p), 1e-5f));
      p = 1.f / (1.f + __expf(-(acc01[r] + b1))); pv01[r] = p;
      s1 += __logf(fmaxf(p * (1.f - p), 1e-5f));
      p = 1.f / (1.f + __expf(-(acc11[r] + b1))); pv11[r] = p;
      s1 += __logf(fmaxf(p * (1.f - p), 1e-5f));
    }
  }
  float rsum;
  {
    const int d0 = 31 - __clz(c0 + 1);
    rsum = s0 * (-0.5f / (8192.0f * (float)(1 << d0)));
    if (v1ok) {
      const int d1 = 31 - __clz(c1 + 1);
      rsum += s1 * (-0.5f / (8192.0f * (float)(1 << d1)));
    }
  }
#pragma unroll
  for (int off = 32; off; off >>= 1) rsum += __shfl_down(rsum, off, 64);

  // ---- write probabilities to L_s (disjoint from xh_s: no WAR barrier) ----
  {
#pragma unroll
    for (int r = 0; r < 4; ++r) {
      const int row0 = q * 4 + r, row1 = row0 + 16;
      L_s[row0 * LSTR + c0] = pv00[r];
      L_s[row0 * LSTR + c1] = pv01[r];   // col 255 in-bounds, never read
      L_s[row1 * LSTR + c0] = pv10[r];
      L_s[row1 * LSTR + c1] = pv11[r];
    }
    if (lane == 0) red_s[w] = rsum;
  }
  __syncthreads();   // barrier 2: L_s + red_s visible

  if (t == 0) {
    float s = 0.f;
#pragma unroll
    for (int i = 0; i < 8; ++i) s += red_s[i];
    atomicAdd(reg_out, s);
  }

  // ---- phase 2b: path products, 8 leaves x 2 rows per thread ----
  {
    const int g8 = t & 31, rp = t >> 5;
    const int Lb = g8 * 8;
#pragma unroll
    for (int rr = 0; rr < 2; ++rr) {
      const int row = rp * 2 + rr;
      const float* Lr = &L_s[row * LSTR];
      float pre = 1.f;
#pragma unroll
      for (int dd = 0; dd < 5; ++dd) {
        float p = Lr[(1 << dd) - 1 + (Lb >> (8 - dd))];
        float br = ((Lb >> (7 - dd)) & 1) ? (1.f - p) : p;
        pre *= fmaxf(br, 1e-5f);
      }
      float p5 = Lr[31 + g8];
      float s5a = fmaxf(p5, 1e-5f), s5b = fmaxf(1.f - p5, 1e-5f);
      float p6a = Lr[63 + 2 * g8], p6b = Lr[63 + 2 * g8 + 1];
      float p7v[4];
#pragma unroll
      for (int m = 0; m < 4; ++m) p7v[m] = Lr[127 + 4 * g8 + m];
      _Float16 ph[8];
#pragma unroll
      for (int j = 0; j < 8; ++j) {
        float s5 = (j & 4) ? s5b : s5a;
        float p6 = (j & 4) ? p6b : p6a;
        float s6 = fmaxf((j & 2) ? (1.f - p6) : p6, 1e-5f);
        float p7 = p7v[j >> 1];
        float s7 = fmaxf((j & 1) ? (1.f - p7) : p7, 1e-5f);
        ph[j] = (_Float16)(pre * s5 * s6 * s7);
      }
      *(half8*)&P_h[row * PSTR + Lb] = *(half8*)ph;
    }
  }
  __syncthreads();   // barrier 3: P_h ready

  // ---- phase 2c: out[32][64] = P @ value via fp16 MFMA ----
  {
    const int tm = w & 1, tn = w >> 1;       // 2 m-tiles x 4 n-tiles of 16
    floatx4 C = {0, 0, 0, 0};
    const _Float16* pa = &P_h[(tm * 16 + r16) * PSTR + q * 8];
#pragma unroll
    for (int kc = 0; kc < 8; ++kc) {
      half8 A8 = *(const half8*)(pa + kc * 32);
      C = __builtin_amdgcn_mfma_f32_16x16x32_f16(A8, VB[kc], C, 0, 0, 0);
    }
    const int col = tn * 16 + r16;
#pragma unroll
    for (int r = 0; r < 4; ++r) {
      int row = tm * 16 + q * 4 + r;
      out[(size_t)(R0 + row) * O + col] = C[r];
    }
  }
}

extern "C" void kernel_launch(void* const* d_in, const int* in_sizes, int n_in,
                              void* d_out, int out_size, void* d_ws, size_t ws_size,
                              hipStream_t stream) {
  const float* x     = (const float*)d_in[0];
  const float* Ws    = (const float*)d_in[1];
  const float* bs    = (const float*)d_in[2];
  const float* value = (const float*)d_in[3];
  float* outp = (float*)d_out;
  float* reg_slot = outp + (size_t)8192 * O;          // index 524288
  _Float16* wt_all = (_Float16*)d_ws;                 // 8 XCD-local copies, 2.3 MB

  sdt_pre<<<1088, 512, 0, stream>>>(Ws, value, wt_all, reg_slot);
  sdt_main<<<256, 512, 0, stream>>>(x, wt_all, bs, outp, reg_slot);
}

// Round 9
// 81.342 us; speedup vs baseline: 1.0144x; 1.0144x over previous
//
#include <hip/hip_runtime.h>

// SDT forward, fp16 MFMA (fp32 accumulate), v10 = exact revert to v8 (session
// best, 80.8us). v9's XCD-replication regressed (-1.7us): bid->XCD alignment
// between pre and main is not guaranteed (dispatch mapping undefined), and
// wt reads were not the exposed term.
// Exonerated levers (each <=1us): TLP/waves (v6), in-loop VMEM (v7), barrier
// count (v7), pre-bubble + vt timing (v8), cache tier (v9). Catastrophic:
// coop grid.sync (v3, +40us), fp32 scalar gather (v5, +35us).
// Accounting: 43us ws-poison fill (harness-fixed) + ~8us fixed resets/graph
// + ~30us pre+gap+main (latency-bound, structurally probed out).
// Layouts (HW-verified): A/B^T lane&15->row(n), (lane>>4)*8->k;
// C/D: col=lane&15, row=(lane>>4)*4+reg.

typedef __attribute__((ext_vector_type(8))) _Float16 half8;
typedef __attribute__((ext_vector_type(4))) _Float16 half4;
typedef __attribute__((ext_vector_type(2))) _Float16 half2v;
typedef __attribute__((ext_vector_type(4))) float floatx4;

constexpr int O = 64;
constexpr int XSTR = 520;   // x-tile LDS row stride (halfs): 1040 B
constexpr int PSTR = 280;   // P_h row stride (halfs): 560 B (16B-aligned)
constexpr int LSTR = 260;   // L_s row stride (floats)

// ---- pre: W^T fp16 frag-major; value^T fp16 frag-major; zero reg ----
// wt layout: block (T*16+c) of 1024 B; lane=(q*16+r16); elem j:
//   wt[(T*16+c)*512 + lane*8 + j] = W[k= c*32+q*8+j][n= T*16+r16]
// W-path 128 blocks x 4 k-rows (2 elems/thread), value 8 blocks x 32 rows.
__global__ __launch_bounds__(512) void sdt_pre(
    const float* __restrict__ Ws, const float* __restrict__ value,
    _Float16* __restrict__ wt, _Float16* __restrict__ vt,
    float* __restrict__ reg_slot)
{
  const int bid = blockIdx.x, t = threadIdx.x;
  if (bid < 128) {                     // W: 4 k-rows per block, coalesced reads
    const int k0 = bid * 4;
    const int n = t & 255, hf = t >> 8;            // hf: which kk-pair
    const int T = n >> 4, r = n & 15;
    const int kA = k0 + hf * 2;                    // first k of this pair
    const int c = kA >> 5, q = (kA >> 3) & 3, j0 = kA & 7;
    _Float16 v2h[2];
#pragma unroll
    for (int i = 0; i < 2; ++i) {
      float f = (n < 255) ? Ws[(size_t)(kA + i) * 255 + n] : 0.f;
      v2h[i] = (_Float16)f;
    }
    *(half2v*)&wt[(size_t)(T * 16 + c) * 512 + (q * 16 + r) * 8 + j0] =
        *(half2v*)v2h;
  } else {                             // value^T: 32 k-rows per block
    const int k0 = (bid - 128) * 32;
#pragma unroll
    for (int j = 0; j < 4; ++j) {
      int e = t + j * 512;             // 0..2047
      int k = k0 + (e >> 6), n = e & 63;
      float f = value[(size_t)k * O + n];
      int T = n >> 4, r = n & 15, kc = k >> 5, q = (k >> 3) & 3, jj = k & 7;
      vt[(size_t)(T * 8 + kc) * 512 + (q * 16 + r) * 8 + jj] = (_Float16)f;
    }
    if (bid == 128 && t == 0) *reg_slot = 0.f;
  }
}

__global__ __launch_bounds__(512, 1) void sdt_main(
    const float* __restrict__ x, const _Float16* __restrict__ wt,
    const _Float16* __restrict__ vt, const float* __restrict__ bs,
    float* __restrict__ out, float* __restrict__ reg_out)
{
  // Disjoint LDS (no overlay): xh 33280 + L_s 33280 + P_h 17920 = 84480 B.
  __shared__ __align__(16) char smem[33280 + 33280 + 17920];
  _Float16* xh_s = (_Float16*)smem;               // [32][520]
  float*    L_s  = (float*)(smem + 33280);        // [32][260]
  _Float16* P_h  = (_Float16*)(smem + 66560);     // [32][280]
  __shared__ float red_s[8];

  const int t = threadIdx.x, lane = t & 63, w = t >> 6;   // 8 waves
  const int q = lane >> 4, r16 = lane & 15;
  const int R0 = blockIdx.x * 32;

  // ---- issue x loads first (HBM, longest latency; oldest -> drain first) ----
  const int xrowi = t >> 4, xl4 = (t & 15) * 4;
  const float* xrow = x + (size_t)(R0 + xrowi) * 512;
  float4 xv[8];
#pragma unroll
  for (int i = 0; i < 8; ++i) xv[i] = *(const float4*)(xrow + xl4 + i * 64);

  // ---- preload ALL 16 B-chunks for both n-tiles (128 VGPRs) ----
  const _Float16* pb0 = wt + (size_t)(2 * w) * 16 * 512 + lane * 8;
  const _Float16* pb1 = wt + (size_t)(2 * w + 1) * 16 * 512 + lane * 8;
  half8 B0[16], B1[16];
#pragma unroll
  for (int c = 0; c < 16; ++c) {
    B0[c] = *(const half8*)(pb0 + c * 512);
    B1[c] = *(const half8*)(pb1 + c * 512);
  }

  // ---- convert + store x tile to LDS ----
#pragma unroll
  for (int i = 0; i < 8; ++i) {
    half4 h = {(_Float16)xv[i].x, (_Float16)xv[i].y,
               (_Float16)xv[i].z, (_Float16)xv[i].w};
    *(half4*)&xh_s[xrowi * XSTR + xl4 + i * 64] = h;
  }
  __syncthreads();   // barrier 1: x tile staged

  // ---- K-loop: 16 chunks of K=32, pure LDS + MFMA (no VMEM) ----
  floatx4 acc00 = {0,0,0,0}, acc01 = {0,0,0,0}, acc10 = {0,0,0,0}, acc11 = {0,0,0,0};
  const int a0off = r16 * XSTR + q * 8, a1off = (16 + r16) * XSTR + q * 8;

#pragma unroll
  for (int c = 0; c < 16; ++c) {
    half8 a0 = *(const half8*)&xh_s[a0off + c * 32];
    half8 a1 = *(const half8*)&xh_s[a1off + c * 32];
    acc00 = __builtin_amdgcn_mfma_f32_16x16x32_f16(a0, B0[c], acc00, 0, 0, 0);
    acc01 = __builtin_amdgcn_mfma_f32_16x16x32_f16(a0, B1[c], acc01, 0, 0, 0);
    acc10 = __builtin_amdgcn_mfma_f32_16x16x32_f16(a1, B0[c], acc10, 0, 0, 0);
    acc11 = __builtin_amdgcn_mfma_f32_16x16x32_f16(a1, B1[c], acc11, 0, 0, 0);
  }

  // ---- vt B-frag prefetch NOW: L3 latency hides under the epilogue ----
  half8 VB[8];
  {
    const int tn = w >> 1;
    const _Float16* vb = vt + (size_t)(tn * 8) * 512 + lane * 8;
#pragma unroll
    for (int kc = 0; kc < 8; ++kc) VB[kc] = *(const half8*)(vb + kc * 512);
  }

  // ---- fused epilogue: bias + sigmoid + reg on registers ----
  const int c0 = w * 32 + r16, c1 = c0 + 16;   // c0 <= 239; c1 <= 255
  const bool v1ok = (c1 < 255);
  float pv00[4], pv01[4], pv10[4], pv11[4];
  float s0 = 0.f, s1 = 0.f;
  {
    const float b0 = bs[c0];
    const float b1 = v1ok ? bs[c1] : 0.f;
#pragma unroll
    for (int r = 0; r < 4; ++r) {
      float p;
      p = 1.f / (1.f + __expf(-(acc00[r] + b0))); pv00[r] = p;
      s0 += __logf(fmaxf(p * (1.f - p), 1e-5f));
      p = 1.f / (1.f + __expf(-(acc10[r] + b0))); pv10[r] = p;
      s0 += __logf(fmaxf(p * (1.f - p), 1e-5f));
      p = 1.f / (1.f + __expf(-(acc01[r] + b1))); pv01[r] = p;
      s1 += __logf(fmaxf(p * (1.f - p), 1e-5f));
      p = 1.f / (1.f + __expf(-(acc11[r] + b1))); pv11[r] = p;
      s1 += __logf(fmaxf(p * (1.f - p), 1e-5f));
    }
  }
  float rsum;
  {
    const int d0 = 31 - __clz(c0 + 1);
    rsum = s0 * (-0.5f / (8192.0f * (float)(1 << d0)));
    if (v1ok) {
      const int d1 = 31 - __clz(c1 + 1);
      rsum += s1 * (-0.5f / (8192.0f * (float)(1 << d1)));
    }
  }
#pragma unroll
  for (int off = 32; off; off >>= 1) rsum += __shfl_down(rsum, off, 64);

  // ---- write probabilities to L_s (disjoint from xh_s: no WAR barrier) ----
  {
#pragma unroll
    for (int r = 0; r < 4; ++r) {
      const int row0 = q * 4 + r, row1 = row0 + 16;
      L_s[row0 * LSTR + c0] = pv00[r];
      L_s[row0 * LSTR + c1] = pv01[r];   // col 255 in-bounds, never read
      L_s[row1 * LSTR + c0] = pv10[r];
      L_s[row1 * LSTR + c1] = pv11[r];
    }
    if (lane == 0) red_s[w] = rsum;
  }
  __syncthreads();   // barrier 2: L_s + red_s visible

  if (t == 0) {
    float s = 0.f;
#pragma unroll
    for (int i = 0; i < 8; ++i) s += red_s[i];
    atomicAdd(reg_out, s);
  }

  // ---- phase 2b: path products, 8 leaves x 2 rows per thread ----
  {
    const int g8 = t & 31, rp = t >> 5;
    const int Lb = g8 * 8;
#pragma unroll
    for (int rr = 0; rr < 2; ++rr) {
      const int row = rp * 2 + rr;
      const float* Lr = &L_s[row * LSTR];
      float pre = 1.f;
#pragma unroll
      for (int dd = 0; dd < 5; ++dd) {
        float p = Lr[(1 << dd) - 1 + (Lb >> (8 - dd))];
        float br = ((Lb >> (7 - dd)) & 1) ? (1.f - p) : p;
        pre *= fmaxf(br, 1e-5f);
      }
      float p5 = Lr[31 + g8];
      float s5a = fmaxf(p5, 1e-5f), s5b = fmaxf(1.f - p5, 1e-5f);
      float p6a = Lr[63 + 2 * g8], p6b = Lr[63 + 2 * g8 + 1];
      float p7v[4];
#pragma unroll
      for (int m = 0; m < 4; ++m) p7v[m] = Lr[127 + 4 * g8 + m];
      _Float16 ph[8];
#pragma unroll
      for (int j = 0; j < 8; ++j) {
        float s5 = (j & 4) ? s5b : s5a;
        float p6 = (j & 4) ? p6b : p6a;
        float s6 = fmaxf((j & 2) ? (1.f - p6) : p6, 1e-5f);
        float p7 = p7v[j >> 1];
        float s7 = fmaxf((j & 1) ? (1.f - p7) : p7, 1e-5f);
        ph[j] = (_Float16)(pre * s5 * s6 * s7);
      }
      *(half8*)&P_h[row * PSTR + Lb] = *(half8*)ph;
    }
  }
  __syncthreads();   // barrier 3: P_h ready

  // ---- phase 2c: out[32][64] = P @ value via fp16 MFMA ----
  {
    const int tm = w & 1, tn = w >> 1;       // 2 m-tiles x 4 n-tiles of 16
    floatx4 C = {0, 0, 0, 0};
    const _Float16* pa = &P_h[(tm * 16 + r16) * PSTR + q * 8];
#pragma unroll
    for (int kc = 0; kc < 8; ++kc) {
      half8 A8 = *(const half8*)(pa + kc * 32);
      C = __builtin_amdgcn_mfma_f32_16x16x32_f16(A8, VB[kc], C, 0, 0, 0);
    }
    const int col = tn * 16 + r16;
#pragma unroll
    for (int r = 0; r < 4; ++r) {
      int row = tm * 16 + q * 4 + r;
      out[(size_t)(R0 + row) * O + col] = C[r];
    }
  }
}

extern "C" void kernel_launch(void* const* d_in, const int* in_sizes, int n_in,
                              void* d_out, int out_size, void* d_ws, size_t ws_size,
                              hipStream_t stream) {
  const float* x     = (const float*)d_in[0];
  const float* Ws    = (const float*)d_in[1];
  const float* bs    = (const float*)d_in[2];
  const float* value = (const float*)d_in[3];
  float* outp = (float*)d_out;
  float* reg_slot = outp + (size_t)8192 * O;          // index 524288
  _Float16* wt = (_Float16*)d_ws;                     // frag-major W^T fp16, 256 KB
  _Float16* vt = wt + 256 * 512;                      // frag-major value^T fp16, 32 KB

  sdt_pre<<<136, 512, 0, stream>>>(Ws, value, wt, vt, reg_slot);
  sdt_main<<<256, 512, 0, stream>>>(x, wt, vt, bs, outp, reg_slot);
}